// Round 6
// baseline (440.280 us; speedup 1.0000x reference)
//
#include <hip/hip_runtime.h>

typedef __attribute__((ext_vector_type(4))) float f32x4;
typedef __attribute__((ext_vector_type(8))) short s16x8;

#define W_DIM   512
#define CHANNELS 1024
#define SPATIAL 4096   /* 64*64 */
#define NB      16

__device__ inline unsigned short f2bf(float x){
  unsigned int u = __float_as_uint(x);
  u += 0x7fffu + ((u >> 16) & 1u);   // round-to-nearest-even
  return (unsigned short)(u >> 16);
}

// sin/cos of 2*pi*x: v_sin_f32/v_cos_f32 take revolutions; fract for domain.
__device__ inline float sin2pi(float x){
  return __builtin_amdgcn_sinf(__builtin_amdgcn_fractf(x));
}
__device__ inline float cos2pi(float x){
  return __builtin_amdgcn_cosf(__builtin_amdgcn_fractf(x));
}

__device__ inline void async_load16(const unsigned short* g, unsigned short* l){
  __builtin_amdgcn_global_load_lds(
      (const __attribute__((address_space(1))) void*)g,
      (__attribute__((address_space(3))) void*)l, 16, 0, 0);
}

// ---------------------------------------------------------------- setup ----
__global__ void sy_setup(const float* __restrict__ w, const float* __restrict__ freqs,
                         const float* __restrict__ phases, const float* __restrict__ affine_w,
                         const float* __restrict__ affine_b, float4* __restrict__ params){
  int b = blockIdx.x;
  int t = threadIdx.x;
  float p0=0.f, p1=0.f, p2=0.f, p3=0.f;
  #pragma unroll
  for (int it = 0; it < 2; ++it){
    int i = t + it*256;
    float wv = w[b*W_DIM + i];
    p0 += wv * affine_w[0*W_DIM + i];
    p1 += wv * affine_w[1*W_DIM + i];
    p2 += wv * affine_w[2*W_DIM + i];
    p3 += wv * affine_w[3*W_DIM + i];
  }
  #pragma unroll
  for (int off = 32; off >= 1; off >>= 1){
    p0 += __shfl_down(p0, off);
    p1 += __shfl_down(p1, off);
    p2 += __shfl_down(p2, off);
    p3 += __shfl_down(p3, off);
  }
  __shared__ float red[4][4];
  __shared__ float sc[4];
  int wave = t >> 6, lane = t & 63;
  if (lane == 0){ red[wave][0]=p0; red[wave][1]=p1; red[wave][2]=p2; red[wave][3]=p3; }
  __syncthreads();
  if (t == 0){
    const float inv_sq = 0.04419417382415922f; // 1/sqrt(512)
    float tv[4];
    #pragma unroll
    for (int j=0;j<4;++j){
      float s = red[0][j]+red[1][j]+red[2][j]+red[3][j];
      tv[j] = s * inv_sq + affine_b[j];
    }
    float n  = sqrtf(tv[0]*tv[0] + tv[1]*tv[1]);
    float iv = 1.0f / n;
    float c = tv[0]*iv, s = tv[1]*iv;
    float t2 = tv[2]*iv, t3 = tv[3]*iv;
    float tcx = -(c*t2 - s*t3);
    float tcy = -(s*t2 + c*t3);
    sc[0]=c; sc[1]=s; sc[2]=tcx; sc[3]=tcy;
  }
  __syncthreads();
  float c = sc[0], s = sc[1], tcx = sc[2], tcy = sc[3];
  #pragma unroll
  for (int j = 0; j < 4; ++j){
    int ci = t + j*256;
    float f0x = freqs[ci*2], f0y = freqs[ci*2+1];
    float fx =  f0x*c + f0y*s;
    float fy = -f0x*s + f0y*c;
    float ph = phases[ci] + f0x*tcx + f0y*tcy;
    float r  = sqrtf(fx*fx + fy*fy);
    float amp = 1.0f - (r - 2.0f) * (1.0f/30.0f);
    amp = fminf(fmaxf(amp, 0.0f), 1.0f);
    float4 P; P.x=fx; P.y=fy; P.z=ph; P.w=amp;
    params[b*CHANNELS + ci] = P;
  }
}

// ------------------------------------------------------ weight -> bf16 -----
__global__ void sy_cvtw(const float* __restrict__ wt, unsigned short* __restrict__ Wbf){
  int i = (blockIdx.x*256 + threadIdx.x)*4;
  float4 v = *(const float4*)(wt + i);
  ushort4 o;
  o.x = f2bf(v.x*0.03125f); o.y = f2bf(v.y*0.03125f);
  o.z = f2bf(v.z*0.03125f); o.w = f2bf(v.w*0.03125f);
  *(ushort4*)(Wbf + i) = o;
}

// ---------------------------------------------------- fused S-gen + GEMM ----
// out[b][row=k][col=m] = sum_c Wbf[row][c] * S[b][col][c], S computed in-LDS.
// Round-1's verified skeleton frozen: 256x256 tile, BK=32, 8 waves (2m x 4n),
// wave C = 128x64 = acc[8][4]; A staged via global_load_lds into 4 slots
// (3 tiles in flight, counted vmcnt, ONE barrier per K-tile).
// B (the sine panel) is now COMPUTED per tile into a 2-slot LDS dbuf:
// 512 threads = 32 ch x (4 h x 4 wseg); each thread runs genS's exact
// recurrence (init sin/cos at wseg*16, 16 rotation steps) and ds_write_b16's
// 16 bf16 values with the same XOR chunk layout the ds_read side uses
// (write: global chunk cg=ch>>3 stored at cg ^ ((col>>1)&3); read:
// xs = (kg ^ ((l15>>1)&3))*8 -- matching involution, rule 21).
// VALU S-work (~170 inst + 6 trans / thread / tile) hides under the 32-MFMA
// cluster (separate pipes, m114); lgkmcnt(0) before the barrier publishes B.
// S values bit-identical to the old sy_genS -> output bit-identical.
__global__ __launch_bounds__(512, 2) void sy_gemm(const unsigned short* __restrict__ Wbf,
                                                  const float4* __restrict__ params,
                                                  float* __restrict__ out){
  __shared__ __align__(16) unsigned short ldsA[4][8192];  // 64 KB: 4 x (256x32)
  __shared__ __align__(16) unsigned short ldsB[2][8192];  // 32 KB: 2 x (256x32)
  const int tid  = threadIdx.x;
  const int lane = tid & 63, wave = tid >> 6;
  const int wm = wave >> 2, wn = wave & 3;

  // block decode, XCD-bijective swizzle (gridDim.x = 1024, %8 == 0)
  const int nwg = gridDim.x;
  const int cpx = nwg >> 3;
  const int bid = blockIdx.x;
  const int sbid = (bid & 7)*cpx + (bid >> 3);
  const int mt  = sbid & 3;          // 4 mt-blocks with same ntl are adjacent
  const int ntl = sbid >> 2;         //  -> same XCD shares the S panel in L2
  const size_t NcolL = (size_t)ntl * 256;
  const int b   = (int)(NcolL >> 12);
  const int nin = (int)(NcolL & 4095);
  const unsigned short* Abase = Wbf + (size_t)mt * 256 * CHANNELS;

  // A staging (round-1 scheme): 1024 chunks of 16B, 2/thread.
  // chunk p: row = p>>2, stored pos p&3 holds global kc = (p&3)^((row>>1)&3)
  int voff[2], loff[2];
  #pragma unroll
  for (int j = 0; j < 2; ++j){
    int p   = (j*8 + wave)*64 + lane;
    int row = p >> 2;
    int kc  = (p & 3) ^ ((row >> 1) & 3);
    voff[j] = row*CHANNELS + kc*8;
    loff[j] = p*8;
  }

  // S-generation assignment: channel chl (0..31), 16-col segment
  const int chl  = tid & 31;
  const int hw   = tid >> 5;           // 0..15
  const int hloc = hw >> 2, wseg = hw & 3;
  const int colbase = hloc*64 + wseg*16;
  const int hglob = (nin >> 6) + hloc;
  const float v  = (hglob + 0.5f)*(1.0f/64.0f) - 0.5f;
  const float u0 = (wseg*16 + 0.5f)*(1.0f/64.0f) - 0.5f;
  const int ch7 = chl & 7, cgc = chl >> 3;
  const float4* Pb = params + (size_t)b*CHANNELS + chl;

  // fragment read offsets (round-1, unchanged; measured 0 bank conflicts)
  const int l15 = lane & 15, kg = lane >> 4;
  const int xs  = (kg ^ ((l15 >> 1) & 3)) * 8;
  const int aoff = (wm*128 + l15)*32 + xs;
  const int boff = (wn*64  + l15)*32 + xs;

  f32x4 acc[8][4];
  #pragma unroll
  for (int i=0;i<8;++i)
    #pragma unroll
    for (int j=0;j<4;++j){
      f32x4 z = {0.f,0.f,0.f,0.f};
      acc[i][j] = z;
    }

  auto STAGE = [&](int kt){
    const int ko = kt*32;
    unsigned short* la = &ldsA[kt & 3][0];
    async_load16(Abase + voff[0] + ko, la + loff[0]);
    async_load16(Abase + voff[1] + ko, la + loff[1]);
  };
  // genS's exact math: identical init points (16-col segments) and
  // identical op sequence -> bit-identical bf16 S values.
  auto SGEN = [&](int kt){
    float4 P = Pb[kt*32];
    float V  = v*P.y + P.z;
    float sV = sin2pi(V)*P.w, cV = cos2pi(V)*P.w;
    float U  = u0*P.x;
    float sU = sin2pi(U), cU = cos2pi(U);
    float D  = P.x * (1.0f/64.0f);
    float sD = sin2pi(D), cD = cos2pi(D);
    unsigned short* bl = &ldsB[kt & 1][0];
    #pragma unroll
    for (int i = 0; i < 16; ++i){
      int col = colbase + i;
      int cl  = cgc ^ ((col >> 1) & 3);     // (col>>1)&3 == (i>>1)&3, colbase%16==0
      bl[col*32 + cl*8 + ch7] = f2bf(sU*cV + cU*sV);
      float ns = sU*cD + cU*sD;
      float nc = cU*cD - sU*sD;
      sU = ns; cU = nc;
    }
  };
  auto COMPUTE = [&](int sA, int sB){
    s16x8 af[8], bv[4];
    #pragma unroll
    for (int mf=0; mf<8; ++mf) af[mf] = *(const s16x8*)&ldsA[sA][aoff + mf*512];
    #pragma unroll
    for (int nf=0; nf<4; ++nf) bv[nf] = *(const s16x8*)&ldsB[sB][boff + nf*512];
    __builtin_amdgcn_s_setprio(1);
    #pragma unroll
    for (int mf=0; mf<8; ++mf)
      #pragma unroll
      for (int nf=0; nf<4; ++nf)
        acc[mf][nf] = __builtin_amdgcn_mfma_f32_16x16x32_bf16(af[mf], bv[nf], acc[mf][nf], 0, 0, 0);
    __builtin_amdgcn_s_setprio(0);
  };

  // prologue: B0 computed, A tiles 0..2 in flight; wait A0 (allow A1,A2)
  SGEN(0);
  STAGE(0); STAGE(1); STAGE(2);
  asm volatile("s_waitcnt lgkmcnt(0)" ::: "memory");   // B0 published
  asm volatile("s_waitcnt vmcnt(4)"   ::: "memory");   // A0 landed
  __builtin_amdgcn_s_barrier();

  // steady: K = 1024 -> 32 tiles of 32
  for (int t = 0; t < 29; ++t){
    SGEN(t + 1);                 // B(t+1) -> slot (t+1)&1 (read at t-1, safe)
    STAGE(t + 3);                // A(t+3) -> slot (t+3)&3 (read at t-1, safe)
    COMPUTE(t & 3, t & 1);
    asm volatile("s_waitcnt lgkmcnt(0)" ::: "memory"); // B(t+1) published
    asm volatile("s_waitcnt vmcnt(4)"   ::: "memory"); // A(t+1) landed
    __builtin_amdgcn_s_barrier();
  }
  SGEN(30);
  COMPUTE(29 & 3, 29 & 1);
  asm volatile("s_waitcnt lgkmcnt(0)" ::: "memory");
  asm volatile("s_waitcnt vmcnt(2)"   ::: "memory");   // A30 landed
  __builtin_amdgcn_s_barrier();
  SGEN(31);
  COMPUTE(30 & 3, 30 & 1);
  asm volatile("s_waitcnt lgkmcnt(0)" ::: "memory");
  asm volatile("s_waitcnt vmcnt(0)"   ::: "memory");   // A31 landed
  __builtin_amdgcn_s_barrier();
  COMPUTE(31 & 3, 31 & 1);

  // C/D layout: col = lane&15, row = (lane>>4)*4 + reg
  float* outb = out + (size_t)b * CHANNELS * SPATIAL;
  const int colb = nin + wn*64 + l15;
  const int row0 = mt*256 + wm*128 + (kg << 2);
  #pragma unroll
  for (int mf = 0; mf < 8; ++mf)
    #pragma unroll
    for (int nf = 0; nf < 4; ++nf)
      #pragma unroll
      for (int r = 0; r < 4; ++r)
        outb[(size_t)(row0 + mf*16 + r) * SPATIAL + colb + nf*16] = acc[mf][nf][r];
}

// ---------------------------------------------- emergency small-ws path ----
__global__ void sy_fallback(const float* __restrict__ weight, const float4* __restrict__ params,
                            float* __restrict__ out){
  extern __shared__ float S[];   // 32*1024 floats = 128 KB
  int b  = blockIdx.x >> 7;
  int m0 = (blockIdx.x & 127) * 32;
  int t  = threadIdx.x;
  {
    int c0 = t*4;
    float4 P0 = params[b*CHANNELS+c0+0], P1 = params[b*CHANNELS+c0+1];
    float4 P2 = params[b*CHANNELS+c0+2], P3 = params[b*CHANNELS+c0+3];
    int h = m0 >> 6;
    float v = (h + 0.5f)*(1.0f/64.0f) - 0.5f;
    float a0 = v*P0.y+P0.z, a1 = v*P1.y+P1.z, a2 = v*P2.y+P2.z, a3 = v*P3.y+P3.z;
    for (int im = 0; im < 32; ++im){
      int wv = (m0+im) & 63;
      float u = (wv+0.5f)*(1.0f/64.0f) - 0.5f;
      float* row = S + im*CHANNELS + c0;
      row[0] = sin2pi(u*P0.x+a0)*P0.w;
      row[1] = sin2pi(u*P1.x+a1)*P1.w;
      row[2] = sin2pi(u*P2.x+a2)*P2.w;
      row[3] = sin2pi(u*P3.x+a3)*P3.w;
    }
  }
  __syncthreads();
  for (int oi = t; oi < 32*1024; oi += 256){
    int k = oi >> 5, im = oi & 31;
    const float4* wr = (const float4*)(weight + (size_t)k*CHANNELS);
    const float4* sr = (const float4*)(S + im*CHANNELS);
    float sum = 0.f;
    for (int c4 = 0; c4 < CHANNELS/4; ++c4){
      float4 a = wr[c4], s4 = sr[c4];
      sum += a.x*s4.x + a.y*s4.y + a.z*s4.z + a.w*s4.w;
    }
    out[((size_t)b*CHANNELS + k)*SPATIAL + m0 + im] = sum * 0.03125f;
  }
}

extern "C" void kernel_launch(void* const* d_in, const int* in_sizes, int n_in,
                              void* d_out, int out_size, void* d_ws, size_t ws_size,
                              hipStream_t stream){
  const float* w        = (const float*)d_in[0];
  const float* freqs    = (const float*)d_in[1];
  const float* phases   = (const float*)d_in[2];
  const float* weight   = (const float*)d_in[3];
  const float* affine_w = (const float*)d_in[4];
  const float* affine_b = (const float*)d_in[5];
  float* out = (float*)d_out;

  char* ws = (char*)d_ws;
  float4* params = (float4*)ws;                       // 256 KB
  const size_t off_w = 262144;                        // Wbf: 2 MiB
  unsigned short* Wbf = (unsigned short*)(ws + off_w);

  sy_setup<<<NB, 256, 0, stream>>>(w, freqs, phases, affine_w, affine_b, params);

  if (ws_size >= off_w + 2097152){
    sy_cvtw<<<1024, 256, 0, stream>>>(weight, Wbf);
    sy_gemm<<<NB*64, 512, 0, stream>>>(Wbf, params, out);
  } else {
    sy_fallback<<<NB*128, 256, 32*1024*4, stream>>>(weight, params, out);
  }
}

// Round 7
// 428.499 us; speedup vs baseline: 1.0275x; 1.0275x over previous
//
#include <hip/hip_runtime.h>

typedef __attribute__((ext_vector_type(4))) float f32x4;
typedef __attribute__((ext_vector_type(8))) short s16x8;
typedef __attribute__((ext_vector_type(8))) unsigned short u16x8;

#define W_DIM   512
#define CHANNELS 1024
#define SPATIAL 4096   /* 64*64 */
#define NB      16

__device__ inline unsigned short f2bf(float x){
  unsigned int u = __float_as_uint(x);
  u += 0x7fffu + ((u >> 16) & 1u);   // round-to-nearest-even
  return (unsigned short)(u >> 16);
}

// sin/cos of 2*pi*x: v_sin_f32/v_cos_f32 take revolutions; fract for domain.
__device__ inline float sin2pi(float x){
  return __builtin_amdgcn_sinf(__builtin_amdgcn_fractf(x));
}
__device__ inline float cos2pi(float x){
  return __builtin_amdgcn_cosf(__builtin_amdgcn_fractf(x));
}

__device__ inline void async_load16(const unsigned short* g, unsigned short* l){
  __builtin_amdgcn_global_load_lds(
      (const __attribute__((address_space(1))) void*)g,
      (__attribute__((address_space(3))) void*)l, 16, 0, 0);
}

// ---------------------------------------------------------------- setup ----
__global__ void sy_setup(const float* __restrict__ w, const float* __restrict__ freqs,
                         const float* __restrict__ phases, const float* __restrict__ affine_w,
                         const float* __restrict__ affine_b, float4* __restrict__ params){
  int b = blockIdx.x;
  int t = threadIdx.x;
  float p0=0.f, p1=0.f, p2=0.f, p3=0.f;
  #pragma unroll
  for (int it = 0; it < 2; ++it){
    int i = t + it*256;
    float wv = w[b*W_DIM + i];
    p0 += wv * affine_w[0*W_DIM + i];
    p1 += wv * affine_w[1*W_DIM + i];
    p2 += wv * affine_w[2*W_DIM + i];
    p3 += wv * affine_w[3*W_DIM + i];
  }
  #pragma unroll
  for (int off = 32; off >= 1; off >>= 1){
    p0 += __shfl_down(p0, off);
    p1 += __shfl_down(p1, off);
    p2 += __shfl_down(p2, off);
    p3 += __shfl_down(p3, off);
  }
  __shared__ float red[4][4];
  __shared__ float sc[4];
  int wave = t >> 6, lane = t & 63;
  if (lane == 0){ red[wave][0]=p0; red[wave][1]=p1; red[wave][2]=p2; red[wave][3]=p3; }
  __syncthreads();
  if (t == 0){
    const float inv_sq = 0.04419417382415922f; // 1/sqrt(512)
    float tv[4];
    #pragma unroll
    for (int j=0;j<4;++j){
      float s = red[0][j]+red[1][j]+red[2][j]+red[3][j];
      tv[j] = s * inv_sq + affine_b[j];
    }
    float n  = sqrtf(tv[0]*tv[0] + tv[1]*tv[1]);
    float iv = 1.0f / n;
    float c = tv[0]*iv, s = tv[1]*iv;
    float t2 = tv[2]*iv, t3 = tv[3]*iv;
    float tcx = -(c*t2 - s*t3);
    float tcy = -(s*t2 + c*t3);
    sc[0]=c; sc[1]=s; sc[2]=tcx; sc[3]=tcy;
  }
  __syncthreads();
  float c = sc[0], s = sc[1], tcx = sc[2], tcy = sc[3];
  #pragma unroll
  for (int j = 0; j < 4; ++j){
    int ci = t + j*256;
    float f0x = freqs[ci*2], f0y = freqs[ci*2+1];
    float fx =  f0x*c + f0y*s;
    float fy = -f0x*s + f0y*c;
    float ph = phases[ci] + f0x*tcx + f0y*tcy;
    float r  = sqrtf(fx*fx + fy*fy);
    float amp = 1.0f - (r - 2.0f) * (1.0f/30.0f);
    amp = fminf(fmaxf(amp, 0.0f), 1.0f);
    float4 P; P.x=fx; P.y=fy; P.z=ph; P.w=amp;
    params[b*CHANNELS + ci] = P;
  }
}

// ------------------------------------------------------ weight -> bf16 -----
__global__ void sy_cvtw(const float* __restrict__ wt, unsigned short* __restrict__ Wbf){
  int i = (blockIdx.x*256 + threadIdx.x)*4;
  float4 v = *(const float4*)(wt + i);
  ushort4 o;
  o.x = f2bf(v.x*0.03125f); o.y = f2bf(v.y*0.03125f);
  o.z = f2bf(v.z*0.03125f); o.w = f2bf(v.w*0.03125f);
  *(ushort4*)(Wbf + i) = o;
}

// ---------------------------------------------------------------- gen S ----
// Separable: sin(2pi(U+V)) = sinU*(cosV*amp) + cosU*(sinV*amp), U=u*fx,
// V=v*fy+ph; (sinU,cosU) advanced by fixed rotation per u step.
__global__ void sy_genS(const float4* __restrict__ params, unsigned short* __restrict__ Sbf,
                        int b0){
  int blk = blockIdx.x;
  int bb  = blk >> 7;
  int b   = b0 + bb;
  int m0  = (blk & 127) * 32;
  int t   = threadIdx.x;
  int c0  = (t & 127) * 8;
  int mh  = t >> 7;              // 0 or 1: which 16-m half
  int h   = m0 >> 6;
  int w0  = (m0 + mh*16) & 63;
  float v  = (h  + 0.5f) * (1.0f/64.0f) - 0.5f;
  float u0 = (w0 + 0.5f) * (1.0f/64.0f) - 0.5f;

  float sU[8], cU[8], sV[8], cV[8], sD[8], cD[8];
  #pragma unroll
  for (int j = 0; j < 8; ++j){
    float4 P = params[b*CHANNELS + c0 + j];
    float V = v*P.y + P.z;
    sV[j] = sin2pi(V) * P.w;
    cV[j] = cos2pi(V) * P.w;
    float U = u0*P.x;
    sU[j] = sin2pi(U);
    cU[j] = cos2pi(U);
    float D = P.x * (1.0f/64.0f);
    sD[j] = sin2pi(D);
    cD[j] = cos2pi(D);
  }

  unsigned short* dst = Sbf + ((size_t)bb * SPATIAL + m0 + mh*16) * CHANNELS + c0;
  for (int im = 0; im < 16; ++im){
    u16x8 o;
    #pragma unroll
    for (int j = 0; j < 8; ++j){
      float val = sU[j]*cV[j] + cU[j]*sV[j];
      o[j] = f2bf(val);
      float ns = sU[j]*cD[j] + cU[j]*sD[j];
      float nc = cU[j]*cD[j] - sU[j]*sD[j];
      sU[j] = ns; cU[j] = nc;
    }
    *(u16x8*)(dst + (size_t)im * CHANNELS) = o;
  }
}

// ----------------------------------------------------------------- GEMM ----
// out[b][row=k][col=m] = sum_c Wbf[row][c] * Sbf[b][col][c].
// 256x256 tile, BK=32, 8 waves (2m x 4n), each wave owns a 128x64 C block
// (acc[8][4] of 16x16 frags). 4-deep LDS pipeline (4 slots x (A+B) x 16KB =
// 128 KiB): while computing tile t from slot t&3, stage tile t+3 into slot
// (t+3)&3 == (t-1)&3, which all waves finished reading before the barrier
// at the end of tile t-1. Counted s_waitcnt vmcnt(8) (2 tiles of 4 issues
// in flight) + raw s_barrier -- no vmcnt(0) drain in the main loop (T4).
// Swizzle (rule 21, both sides): LDS chunk p (16B) holds global
// (row = p>>2, kc = (p&3) ^ ((row>>1)&3)); gload_lds dest stays linear,
// the XOR is applied to the global source and again on the ds_read side.
// Bank check: ds_read_b128 lanes land 2-way max per bank (free, m136).
// VERIFIED 117 us / MfmaUtil 49 / 0 conflicts (round 1). FROZEN.
__global__ __launch_bounds__(512, 2) void sy_gemm(const unsigned short* __restrict__ Wbf,
                                                  const unsigned short* __restrict__ Sbf,
                                                  float* __restrict__ out, int b0){
  __shared__ __align__(16) unsigned short lds[4][2][8192];  // 128 KiB
  const int tid  = threadIdx.x;
  const int lane = tid & 63, wave = tid >> 6;
  const int wm = wave >> 2, wn = wave & 3;

  // block decode, XCD-bijective swizzle (gridDim.x = 64*g, always %8 == 0)
  const int nwg = gridDim.x;
  const int cpx = nwg >> 3;
  const int bid = blockIdx.x;
  const int sbid = (bid & 7)*cpx + (bid >> 3);
  const int mt  = sbid & 3;          // 4 mt-blocks with same ntl are adjacent
  const int ntl = sbid >> 2;         //  -> same XCD L2 shares the S panel
  const size_t NcolL = (size_t)ntl * 256;     // column within this group
  const int bbl = (int)(NcolL >> 12);
  const int nin = (int)(NcolL & 4095);
  const unsigned short* Abase = Wbf + (size_t)mt * 256 * CHANNELS;
  const unsigned short* Bbase = Sbf + NcolL * CHANNELS;

  // staging: 1024 chunks per operand tile; thread covers p=(j*8+wave)*64+lane
  int voff[2], loff[2];
  #pragma unroll
  for (int j = 0; j < 2; ++j){
    int p   = (j*8 + wave)*64 + lane;
    int row = p >> 2;
    int kcg = (p & 3) ^ ((row >> 1) & 3);
    voff[j] = row*CHANNELS + kcg*8;   // global short offset (minus k origin)
    loff[j] = p*8;                    // linear LDS short offset
  }

  // fragment read offsets (shorts): row = base + l15, kc = kg; XOR'd chunk.
  // ((row>>1)&3) is invariant in mf/nf steps of 16 rows and in wm/wn.
  const int l15 = lane & 15, kg = lane >> 4;
  const int xs  = (kg ^ ((l15 >> 1) & 3)) * 8;
  const int aoff = (wm*128 + l15)*32 + xs;
  const int boff = (wn*64  + l15)*32 + xs;

  f32x4 acc[8][4];
  #pragma unroll
  for (int i=0;i<8;++i)
    #pragma unroll
    for (int j=0;j<4;++j){
      f32x4 z = {0.f,0.f,0.f,0.f};
      acc[i][j] = z;
    }

  auto STAGE = [&](int kt){
    const int ko = kt*32;
    unsigned short* la = (unsigned short*)&lds[kt & 3][0][0];
    unsigned short* lb = (unsigned short*)&lds[kt & 3][1][0];
    #pragma unroll
    for (int j = 0; j < 2; ++j){
      async_load16(Abase + voff[j] + ko, la + loff[j]);
      async_load16(Bbase + voff[j] + ko, lb + loff[j]);
    }
  };
  auto COMPUTE = [&](int s){
    s16x8 af[8], bv[4];
    #pragma unroll
    for (int mf = 0; mf < 8; ++mf) af[mf] = *(const s16x8*)&lds[s][0][aoff + mf*512];
    #pragma unroll
    for (int nf = 0; nf < 4; ++nf) bv[nf] = *(const s16x8*)&lds[s][1][boff + nf*512];
    __builtin_amdgcn_s_setprio(1);
    #pragma unroll
    for (int mf = 0; mf < 8; ++mf)
      #pragma unroll
      for (int nf = 0; nf < 4; ++nf)
        acc[mf][nf] = __builtin_amdgcn_mfma_f32_16x16x32_bf16(af[mf], bv[nf], acc[mf][nf], 0, 0, 0);
    __builtin_amdgcn_s_setprio(0);
  };

  // prologue: tiles 0..2 in flight; wait tile 0 (allow 8 = tiles 1,2)
  STAGE(0); STAGE(1); STAGE(2);
  asm volatile("s_waitcnt vmcnt(8)" ::: "memory");
  __builtin_amdgcn_s_barrier();

  // steady state: K = 1024 -> 32 tiles of 32
  for (int t = 0; t < 29; ++t){
    STAGE(t + 3);
    COMPUTE(t & 3);
    asm volatile("s_waitcnt vmcnt(8)" ::: "memory");   // tile t+1 landed
    __builtin_amdgcn_s_barrier();
  }
  COMPUTE(29 & 3);
  asm volatile("s_waitcnt vmcnt(4)" ::: "memory");     // tile 30 landed
  __builtin_amdgcn_s_barrier();
  COMPUTE(30 & 3);
  asm volatile("s_waitcnt vmcnt(0)" ::: "memory");     // tile 31 landed
  __builtin_amdgcn_s_barrier();
  COMPUTE(31 & 3);

  // C/D layout: col = lane&15, row = (lane>>4)*4 + reg
  float* outb = out + (size_t)(b0 + bbl) * CHANNELS * SPATIAL;
  const int colb = nin + wn*64 + l15;
  const int row0 = mt*256 + wm*128 + (kg << 2);
  #pragma unroll
  for (int mf = 0; mf < 8; ++mf)
    #pragma unroll
    for (int nf = 0; nf < 4; ++nf)
      #pragma unroll
      for (int r = 0; r < 4; ++r)
        outb[(size_t)(row0 + mf*16 + r) * SPATIAL + colb + nf*16] = acc[mf][nf][r];
}

// ---------------------------------------------- emergency small-ws path ----
__global__ void sy_fallback(const float* __restrict__ weight, const float4* __restrict__ params,
                            float* __restrict__ out){
  extern __shared__ float S[];   // 32*1024 floats = 128 KB
  int b  = blockIdx.x >> 7;
  int m0 = (blockIdx.x & 127) * 32;
  int t  = threadIdx.x;
  {
    int c0 = t*4;
    float4 P0 = params[b*CHANNELS+c0+0], P1 = params[b*CHANNELS+c0+1];
    float4 P2 = params[b*CHANNELS+c0+2], P3 = params[b*CHANNELS+c0+3];
    int h = m0 >> 6;
    float v = (h + 0.5f)*(1.0f/64.0f) - 0.5f;
    float a0 = v*P0.y+P0.z, a1 = v*P1.y+P1.z, a2 = v*P2.y+P2.z, a3 = v*P3.y+P3.z;
    for (int im = 0; im < 32; ++im){
      int wv = (m0+im) & 63;
      float u = (wv+0.5f)*(1.0f/64.0f) - 0.5f;
      float* row = S + im*CHANNELS + c0;
      row[0] = sin2pi(u*P0.x+a0)*P0.w;
      row[1] = sin2pi(u*P1.x+a1)*P1.w;
      row[2] = sin2pi(u*P2.x+a2)*P2.w;
      row[3] = sin2pi(u*P3.x+a3)*P3.w;
    }
  }
  __syncthreads();
  for (int oi = t; oi < 32*1024; oi += 256){
    int k = oi >> 5, im = oi & 31;
    const float4* wr = (const float4*)(weight + (size_t)k*CHANNELS);
    const float4* sr = (const float4*)(S + im*CHANNELS);
    float sum = 0.f;
    for (int c4 = 0; c4 < CHANNELS/4; ++c4){
      float4 a = wr[c4], s4 = sr[c4];
      sum += a.x*s4.x + a.y*s4.y + a.z*s4.z + a.w*s4.w;
    }
    out[((size_t)b*CHANNELS + k)*SPATIAL + m0 + im] = sum * 0.03125f;
  }
}

extern "C" void kernel_launch(void* const* d_in, const int* in_sizes, int n_in,
                              void* d_out, int out_size, void* d_ws, size_t ws_size,
                              hipStream_t stream){
  const float* w        = (const float*)d_in[0];
  const float* freqs    = (const float*)d_in[1];
  const float* phases   = (const float*)d_in[2];
  const float* weight   = (const float*)d_in[3];
  const float* affine_w = (const float*)d_in[4];
  const float* affine_b = (const float*)d_in[5];
  float* out = (float*)d_out;

  char* ws = (char*)d_ws;
  float4* params = (float4*)ws;                       // 256 KB
  const size_t off_w = 262144;                        // Wbf: 2 MiB
  const size_t off_s = off_w + 2097152;               // Sbf: up to 128 MiB
  unsigned short* Wbf = (unsigned short*)(ws + off_w);
  unsigned short* Sbf = (unsigned short*)(ws + off_s);
  const size_t per_batch = (size_t)SPATIAL * CHANNELS * 2;  // 8 MiB

  sy_setup<<<NB, 256, 0, stream>>>(w, freqs, phases, affine_w, affine_b, params);

  int G = 0;
  if (ws_size >= off_s + per_batch){
    size_t avail = (ws_size - off_s) / per_batch;
    G = avail >= (size_t)NB ? NB : (int)avail;
  }
  if (G == 0){
    sy_fallback<<<NB*128, 256, 32*1024*4, stream>>>(weight, params, out);
    return;
  }
  sy_cvtw<<<1024, 256, 0, stream>>>(weight, Wbf);
  for (int b0 = 0; b0 < NB; b0 += G){
    int g = (NB - b0) < G ? (NB - b0) : G;
    sy_genS<<<g*128, 256, 0, stream>>>(params, Sbf, b0);
    sy_gemm<<<g*64, 512, 0, stream>>>(Wbf, Sbf, out, b0);
  }
}